// Round 1
// baseline (293.578 us; speedup 1.0000x reference)
//
#include <hip/hip_runtime.h>

// StandardAttention: B=2,S=2048,D=1024,H=16,DQK=DV=64. fp32 in/out, bf16 MFMA inside.
// Workspace layout (needs 56 MB):
//   xb  [4096][1024] bf16           8 MB
//   WT  [4][1024][1024] bf16 (W^T)  8 MB
//   Q,K,V [B][H][S][64] bf16        24 MB
//   Vt  [B][H][64][S] bf16          8 MB
//   AO  [B][S][1024] bf16           8 MB

typedef float  f32x4  __attribute__((ext_vector_type(4)));
typedef __bf16 bf16x8 __attribute__((ext_vector_type(8)));

__device__ __forceinline__ unsigned short f2bf(float f) {
    __bf16 h = (__bf16)f;
    return __builtin_bit_cast(unsigned short, h);
}

// ---------------- cast x -> bf16 ----------------
__global__ __launch_bounds__(256) void castx(const float* __restrict__ x,
                                             unsigned short* __restrict__ xb) {
    size_t i = ((size_t)blockIdx.x * 256 + threadIdx.x) * 4;
    float4 v = *(const float4*)(x + i);
    ushort4 o;
    o.x = f2bf(v.x); o.y = f2bf(v.y); o.z = f2bf(v.z); o.w = f2bf(v.w);
    *(ushort4*)(xb + i) = o;
}

// ---------------- transpose+cast weights: W[1024][1024] f32 -> WT[z][1024][1024] bf16 ----
__global__ __launch_bounds__(256) void wtrans(const float* __restrict__ W0,
                                              const float* __restrict__ W1,
                                              const float* __restrict__ W2,
                                              const float* __restrict__ W3,
                                              unsigned short* __restrict__ WT) {
    __shared__ float T[64][65];
    const int z = blockIdx.z;
    const float* W = (z == 0) ? W0 : (z == 1) ? W1 : (z == 2) ? W2 : W3;
    const int k0 = blockIdx.y * 64, n0 = blockIdx.x * 64;
    const int tid = threadIdx.x;
#pragma unroll
    for (int i = 0; i < 4; i++) {
        int c = tid + i * 256;            // 1024 float4 chunks
        int r = c >> 4, col = (c & 15) * 4;
        float4 v = *(const float4*)(W + (size_t)(k0 + r) * 1024 + n0 + col);
        T[r][col] = v.x; T[r][col + 1] = v.y; T[r][col + 2] = v.z; T[r][col + 3] = v.w;
    }
    __syncthreads();
    unsigned short* out = WT + (size_t)z * 1024 * 1024;
#pragma unroll
    for (int i = 0; i < 2; i++) {
        int c = tid + i * 256;            // 512 chunks of 8 bf16
        int nr = c >> 3, koff = (c & 7) * 8;
        union { unsigned short us[8]; uint4 v; } pk;
#pragma unroll
        for (int j = 0; j < 8; j++) pk.us[j] = f2bf(T[koff + j][nr]);
        *(uint4*)(out + (size_t)(n0 + nr) * 1024 + k0 + koff) = pk.v;
    }
}

// ---------------- transpose V [bh][2048][64] -> Vt [bh][64][2048] (bf16) ----------------
__global__ __launch_bounds__(256) void vtrans(const unsigned short* __restrict__ V,
                                              unsigned short* __restrict__ Vt) {
    __shared__ unsigned short T[64][72];
    const int bh = blockIdx.y, s0 = blockIdx.x * 64;
    const int tid = threadIdx.x;
#pragma unroll
    for (int i = 0; i < 2; i++) {
        int c = tid + i * 256;
        int r = c >> 3, dc = (c & 7) * 8;
        *(uint4*)&T[r][dc] = *(const uint4*)(V + ((size_t)(bh * 2048 + s0 + r) << 6) + dc);
    }
    __syncthreads();
#pragma unroll
    for (int i = 0; i < 2; i++) {
        int c = tid + i * 256;
        int dr = c >> 3, soff = (c & 7) * 8;
        union { unsigned short us[8]; uint4 v; } pk;
#pragma unroll
        for (int j = 0; j < 8; j++) pk.us[j] = T[soff + j][dr];
        *(uint4*)(Vt + ((size_t)bh * 64 + dr) * 2048 + s0 + soff) = pk.v;
    }
}

// ---------------- GEMM: C[4096][1024] = A[4096][1024] @ BT[n][k]^T  (bf16 in, f32 acc) ---
// mode 0: write bf16 to outq in [B][H][S][64] layout (+z offset per matrix)
// mode 1: write f32 row-major to outf
__global__ __launch_bounds__(256) void gemm_bt(const unsigned short* __restrict__ A,
                                               const unsigned short* __restrict__ BTall,
                                               unsigned short* __restrict__ outq,
                                               float* __restrict__ outf,
                                               int mode) {
    __shared__ unsigned short As[128 * 40];   // 128 rows x 32 k, stride 40 (bank-friendly)
    __shared__ unsigned short Bs[128 * 40];
    const int tid = threadIdx.x;
    const int w = tid >> 6, lane = tid & 63, quad = lane >> 4, ln = lane & 15;
    const int m0 = blockIdx.y * 128, n0 = blockIdx.x * 128;
    const unsigned short* BT = BTall + (size_t)blockIdx.z * (1024 * 1024);

    const int c0 = tid, c1 = tid + 256;
    const int ar0 = c0 >> 2, ak0 = (c0 & 3) * 8;
    const int ar1 = c1 >> 2, ak1 = (c1 & 3) * 8;

    const f32x4 z4 = {0.f, 0.f, 0.f, 0.f};
    f32x4 acc[4][4];
#pragma unroll
    for (int i = 0; i < 4; i++)
#pragma unroll
        for (int j = 0; j < 4; j++) acc[i][j] = z4;

    const int wm = (w & 1) * 64, wn = (w >> 1) * 64;

    for (int k0 = 0; k0 < 1024; k0 += 32) {
        uint4 a0 = *(const uint4*)(A + (size_t)(m0 + ar0) * 1024 + k0 + ak0);
        uint4 a1 = *(const uint4*)(A + (size_t)(m0 + ar1) * 1024 + k0 + ak1);
        uint4 b0 = *(const uint4*)(BT + (size_t)(n0 + ar0) * 1024 + k0 + ak0);
        uint4 b1 = *(const uint4*)(BT + (size_t)(n0 + ar1) * 1024 + k0 + ak1);
        __syncthreads();
        *(uint4*)&As[ar0 * 40 + ak0] = a0;
        *(uint4*)&As[ar1 * 40 + ak1] = a1;
        *(uint4*)&Bs[ar0 * 40 + ak0] = b0;
        *(uint4*)&Bs[ar1 * 40 + ak1] = b1;
        __syncthreads();
        bf16x8 af[4], bfr[4];
#pragma unroll
        for (int t = 0; t < 4; t++)
            af[t] = *(const bf16x8*)&As[(wm + t * 16 + ln) * 40 + quad * 8];
#pragma unroll
        for (int t = 0; t < 4; t++)
            bfr[t] = *(const bf16x8*)&Bs[(wn + t * 16 + ln) * 40 + quad * 8];
#pragma unroll
        for (int tm = 0; tm < 4; tm++)
#pragma unroll
            for (int tn = 0; tn < 4; tn++)
                acc[tm][tn] = __builtin_amdgcn_mfma_f32_16x16x32_bf16(
                    af[tm], bfr[tn], acc[tm][tn], 0, 0, 0);
    }

#pragma unroll
    for (int tm = 0; tm < 4; tm++)
#pragma unroll
        for (int tn = 0; tn < 4; tn++) {
            int mg = m0 + wm + tm * 16 + quad * 4;
            int ng = n0 + wn + tn * 16 + ln;
#pragma unroll
            for (int r = 0; r < 4; r++) {
                float v = acc[tm][tn][r];
                int m = mg + r;
                if (mode == 0) {
                    int b = m >> 11, s = m & 2047, h = ng >> 6, d = ng & 63;
                    size_t zoff = (size_t)blockIdx.z * (4096 * 1024);
                    outq[zoff + (((size_t)(b * 16 + h) * 2048 + s) << 6) + d] = f2bf(v);
                } else {
                    outf[(size_t)m * 1024 + ng] = v;
                }
            }
        }
}

// ---------------- flash attention (causal, online softmax) ----------------
// Q,K: [bh][2048][64] bf16 ; Vt: [bh][64][2048] bf16 ; AO: [B][S][1024] bf16
#define FD 72
__global__ __launch_bounds__(256) void flash(const unsigned short* __restrict__ Qb,
                                             const unsigned short* __restrict__ Kb,
                                             const unsigned short* __restrict__ Vtb,
                                             unsigned short* __restrict__ AO) {
    __shared__ unsigned short Qs[128 * FD];
    __shared__ unsigned short Ks[64 * FD];
    __shared__ unsigned short Vs[64 * FD];     // V^T tile: row=d, col=k-local
    __shared__ unsigned short Ps[4 * 32 * FD]; // per-wave P (32 rows x 64 cols)
    const int tid = threadIdx.x, w = tid >> 6, lane = tid & 63;
    const int quad = lane >> 4, ln = lane & 15;
    const int bh = blockIdx.y;
    const int q0 = blockIdx.x * 128;
    const unsigned short* Qg = Qb + ((size_t)bh * 2048 + q0) * 64;
    const unsigned short* Kg = Kb + (size_t)bh * 2048 * 64;
    const unsigned short* Vg = Vtb + (size_t)bh * 64 * 2048;

#pragma unroll
    for (int i = 0; i < 4; i++) {
        int c = tid + i * 256;
        int r = c >> 3, kc = (c & 7) * 8;
        *(uint4*)&Qs[r * FD + kc] = *(const uint4*)(Qg + (size_t)r * 64 + kc);
    }

    const f32x4 z4 = {0.f, 0.f, 0.f, 0.f};
    float mrow[2][4], lrow[2][4];
    f32x4 Oc[2][4];
#pragma unroll
    for (int a = 0; a < 2; a++)
#pragma unroll
        for (int r = 0; r < 4; r++) { mrow[a][r] = -INFINITY; lrow[a][r] = 0.f; }
#pragma unroll
    for (int a = 0; a < 2; a++)
#pragma unroll
        for (int b = 0; b < 4; b++) Oc[a][b] = z4;

    const int kend = q0 + 128;
    const int myrow_hi = q0 + w * 32 + 31;
    unsigned short* Pw = Ps + w * 32 * FD;

    for (int k0 = 0; k0 < kend; k0 += 64) {
        __syncthreads();
        {
            int c = tid, r = c >> 3, kc = (c & 7) * 8;
            *(uint4*)&Ks[r * FD + kc] = *(const uint4*)(Kg + (size_t)(k0 + r) * 64 + kc);
            *(uint4*)&Vs[r * FD + kc] = *(const uint4*)(Vg + (size_t)r * 2048 + k0 + kc);
            c = tid + 256; r = c >> 3; kc = (c & 7) * 8;
            *(uint4*)&Ks[r * FD + kc] = *(const uint4*)(Kg + (size_t)(k0 + r) * 64 + kc);
            *(uint4*)&Vs[r * FD + kc] = *(const uint4*)(Vg + (size_t)r * 2048 + k0 + kc);
        }
        __syncthreads();
        const bool active = (k0 <= myrow_hi);   // wave-uniform
        if (active) {
            bf16x8 aq[2][2], bk[4][2];
#pragma unroll
            for (int tm = 0; tm < 2; tm++)
#pragma unroll
                for (int ks = 0; ks < 2; ks++)
                    aq[tm][ks] = *(const bf16x8*)&Qs[(w * 32 + tm * 16 + ln) * FD + ks * 32 + quad * 8];
#pragma unroll
            for (int tn = 0; tn < 4; tn++)
#pragma unroll
                for (int ks = 0; ks < 2; ks++)
                    bk[tn][ks] = *(const bf16x8*)&Ks[(tn * 16 + ln) * FD + ks * 32 + quad * 8];
            f32x4 sc[2][4];
#pragma unroll
            for (int tm = 0; tm < 2; tm++)
#pragma unroll
                for (int tn = 0; tn < 4; tn++) sc[tm][tn] = z4;
#pragma unroll
            for (int tm = 0; tm < 2; tm++)
#pragma unroll
                for (int tn = 0; tn < 4; tn++) {
                    sc[tm][tn] = __builtin_amdgcn_mfma_f32_16x16x32_bf16(aq[tm][0], bk[tn][0], sc[tm][tn], 0, 0, 0);
                    sc[tm][tn] = __builtin_amdgcn_mfma_f32_16x16x32_bf16(aq[tm][1], bk[tn][1], sc[tm][tn], 0, 0, 0);
                }
            const bool edge = (k0 + 63 > q0 + w * 32);
#pragma unroll
            for (int tm = 0; tm < 2; tm++) {
                int rbase = q0 + w * 32 + tm * 16 + quad * 4;
#pragma unroll
                for (int r = 0; r < 4; r++) {
                    int rowg = rbase + r;
                    float sv[4];
                    float mx = -INFINITY;
#pragma unroll
                    for (int tn = 0; tn < 4; tn++) {
                        float v = sc[tm][tn][r] * 0.125f;
                        int colg = k0 + tn * 16 + ln;
                        if (edge && colg > rowg) v = -INFINITY;
                        sv[tn] = v;
                        mx = fmaxf(mx, v);
                    }
#pragma unroll
                    for (int off = 1; off < 16; off <<= 1) mx = fmaxf(mx, __shfl_xor(mx, off));
                    float mold = mrow[tm][r];
                    float mnew = fmaxf(mold, mx);
                    float alpha = __expf(mold - mnew);
                    mrow[tm][r] = mnew;
                    float rs = 0.f;
#pragma unroll
                    for (int tn = 0; tn < 4; tn++) {
                        float p = __expf(sv[tn] - mnew);
                        rs += p;
                        Pw[(tm * 16 + quad * 4 + r) * FD + tn * 16 + ln] = f2bf(p);
                    }
#pragma unroll
                    for (int off = 1; off < 16; off <<= 1) rs += __shfl_xor(rs, off);
                    lrow[tm][r] = lrow[tm][r] * alpha + rs;
#pragma unroll
                    for (int tn = 0; tn < 4; tn++) Oc[tm][tn][r] *= alpha;
                }
            }
        }
        __syncthreads();
        if (active) {
            bf16x8 ap[2][2], bv[4][2];
#pragma unroll
            for (int tm = 0; tm < 2; tm++)
#pragma unroll
                for (int ks = 0; ks < 2; ks++)
                    ap[tm][ks] = *(const bf16x8*)&Pw[(tm * 16 + ln) * FD + ks * 32 + quad * 8];
#pragma unroll
            for (int tn = 0; tn < 4; tn++)
#pragma unroll
                for (int ks = 0; ks < 2; ks++)
                    bv[tn][ks] = *(const bf16x8*)&Vs[(tn * 16 + ln) * FD + ks * 32 + quad * 8];
#pragma unroll
            for (int tm = 0; tm < 2; tm++)
#pragma unroll
                for (int tn = 0; tn < 4; tn++) {
                    Oc[tm][tn] = __builtin_amdgcn_mfma_f32_16x16x32_bf16(ap[tm][0], bv[tn][0], Oc[tm][tn], 0, 0, 0);
                    Oc[tm][tn] = __builtin_amdgcn_mfma_f32_16x16x32_bf16(ap[tm][1], bv[tn][1], Oc[tm][tn], 0, 0, 0);
                }
        }
    }

    const int b = bh >> 4, h = bh & 15;
#pragma unroll
    for (int tm = 0; tm < 2; tm++)
#pragma unroll
        for (int tn = 0; tn < 4; tn++)
#pragma unroll
            for (int r = 0; r < 4; r++) {
                int rowg = q0 + w * 32 + tm * 16 + quad * 4 + r;
                float v = Oc[tm][tn][r] / lrow[tm][r];
                AO[((size_t)(b * 2048 + rowg) << 10) + h * 64 + tn * 16 + ln] = f2bf(v);
            }
}

extern "C" void kernel_launch(void* const* d_in, const int* in_sizes, int n_in,
                              void* d_out, int out_size, void* d_ws, size_t ws_size,
                              hipStream_t stream) {
    const float* x  = (const float*)d_in[0];
    const float* Wq = (const float*)d_in[1];
    const float* Wk = (const float*)d_in[2];
    const float* Wv = (const float*)d_in[3];
    const float* Wo = (const float*)d_in[4];
    float* out = (float*)d_out;

    unsigned short* xb  = (unsigned short*)d_ws;           // 4096*1024
    unsigned short* WT  = xb  + (size_t)4096 * 1024;       // 4*1024*1024
    unsigned short* Qb  = WT  + (size_t)4 * 1024 * 1024;   // Q,K,V contiguous
    unsigned short* Kb  = Qb  + (size_t)4096 * 1024;
    unsigned short* Vb  = Kb  + (size_t)4096 * 1024;
    unsigned short* Vtb = Vb  + (size_t)4096 * 1024;
    unsigned short* AO  = Vtb + (size_t)4096 * 1024;
    // total: 56 MB of workspace

    castx<<<4096, 256, 0, stream>>>(x, xb);
    wtrans<<<dim3(16, 16, 4), 256, 0, stream>>>(Wq, Wk, Wv, Wo, WT);
    gemm_bt<<<dim3(8, 32, 3), 256, 0, stream>>>(xb, WT, Qb, nullptr, 0);
    vtrans<<<dim3(32, 32), 256, 0, stream>>>(Vb, Vtb);
    flash<<<dim3(16, 32), 256, 0, stream>>>(Qb, Kb, Vtb, AO);
    gemm_bt<<<dim3(8, 32, 1), 256, 0, stream>>>(AO, WT + (size_t)3 * 1024 * 1024,
                                                nullptr, out, 1);
}

// Round 2
// 232.089 us; speedup vs baseline: 1.2649x; 1.2649x over previous
//
#include <hip/hip_runtime.h>

// StandardAttention: B=2,S=2048,D=1024,H=16,DQK=DV=64. fp32 in/out, bf16 MFMA inside.
// Workspace layout (56 MB):
//   xb  [4096][1024] bf16           8 MB
//   WT  [4][1024][1024] bf16 (W^T)  8 MB
//   Q,K,V [B][H][S][64] bf16        24 MB   (Q pre-scaled by 0.125*log2(e))
//   Vt  [B][H][64][S] bf16          8 MB
//   AO  [B][S][1024] bf16           8 MB

typedef float  f32x4  __attribute__((ext_vector_type(4)));
typedef __bf16 bf16x8 __attribute__((ext_vector_type(8)));

__device__ __forceinline__ unsigned short f2bf(float f) {
    __bf16 h = (__bf16)f;
    return __builtin_bit_cast(unsigned short, h);
}

// async global->LDS, 16B per lane; lds base must be wave-uniform (HW: base + lane*16)
__device__ __forceinline__ void gld16(unsigned short* lds, const unsigned short* g) {
    __builtin_amdgcn_global_load_lds(
        (const __attribute__((address_space(1))) void*)g,
        (__attribute__((address_space(3))) void*)lds, 16, 0, 0);
}

// ---------------- cast x -> bf16 ----------------
__global__ __launch_bounds__(256) void castx(const float* __restrict__ x,
                                             unsigned short* __restrict__ xb) {
    size_t i = ((size_t)blockIdx.x * 256 + threadIdx.x) * 4;
    float4 v = *(const float4*)(x + i);
    ushort4 o;
    o.x = f2bf(v.x); o.y = f2bf(v.y); o.z = f2bf(v.z); o.w = f2bf(v.w);
    *(ushort4*)(xb + i) = o;
}

// ---------------- transpose+cast weights: W[1024][1024] f32 -> WT[z][1024][1024] bf16 ----
__global__ __launch_bounds__(256) void wtrans(const float* __restrict__ W0,
                                              const float* __restrict__ W1,
                                              const float* __restrict__ W2,
                                              const float* __restrict__ W3,
                                              unsigned short* __restrict__ WT) {
    __shared__ float T[64][65];
    const int z = blockIdx.z;
    const float* W = (z == 0) ? W0 : (z == 1) ? W1 : (z == 2) ? W2 : W3;
    const int k0 = blockIdx.y * 64, n0 = blockIdx.x * 64;
    const int tid = threadIdx.x;
#pragma unroll
    for (int i = 0; i < 4; i++) {
        int c = tid + i * 256;
        int r = c >> 4, col = (c & 15) * 4;
        float4 v = *(const float4*)(W + (size_t)(k0 + r) * 1024 + n0 + col);
        T[r][col] = v.x; T[r][col + 1] = v.y; T[r][col + 2] = v.z; T[r][col + 3] = v.w;
    }
    __syncthreads();
    unsigned short* out = WT + (size_t)z * 1024 * 1024;
#pragma unroll
    for (int i = 0; i < 2; i++) {
        int c = tid + i * 256;
        int nr = c >> 3, koff = (c & 7) * 8;
        union { unsigned short us[8]; uint4 v; } pk;
#pragma unroll
        for (int j = 0; j < 8; j++) pk.us[j] = f2bf(T[koff + j][nr]);
        *(uint4*)(out + (size_t)(n0 + nr) * 1024 + k0 + koff) = pk.v;
    }
}

// ---------------- transpose V [bh][2048][64] -> Vt [bh][64][2048] (bf16) ----------------
__global__ __launch_bounds__(256) void vtrans(const unsigned short* __restrict__ V,
                                              unsigned short* __restrict__ Vt) {
    __shared__ unsigned short T[64][72];
    const int bh = blockIdx.y, s0 = blockIdx.x * 64;
    const int tid = threadIdx.x;
#pragma unroll
    for (int i = 0; i < 2; i++) {
        int c = tid + i * 256;
        int r = c >> 3, dc = (c & 7) * 8;
        *(uint4*)&T[r][dc] = *(const uint4*)(V + ((size_t)(bh * 2048 + s0 + r) << 6) + dc);
    }
    __syncthreads();
#pragma unroll
    for (int i = 0; i < 2; i++) {
        int c = tid + i * 256;
        int dr = c >> 3, soff = (c & 7) * 8;
        union { unsigned short us[8]; uint4 v; } pk;
#pragma unroll
        for (int j = 0; j < 8; j++) pk.us[j] = T[soff + j][dr];
        *(uint4*)(Vt + ((size_t)bh * 64 + dr) * 2048 + s0 + soff) = pk.v;
    }
}

// ---------------- GEMM (m97 structure): C[4096][1024] = A @ BT^T, global_load_lds staging
// mode 0: write bf16 scattered to [B][H][S][64] (+z per matrix); z==0 scaled by 0.125*log2e
// mode 1: write f32 row-major
__global__ __launch_bounds__(256) void gemm_bt(const unsigned short* __restrict__ A,
                                               const unsigned short* __restrict__ BTall,
                                               unsigned short* __restrict__ outq,
                                               float* __restrict__ outf,
                                               int mode) {
    __shared__ unsigned short As[128 * 32];   // unpadded: b128 frag reads are at bank floor
    __shared__ unsigned short Bs[128 * 32];
    const int tid = threadIdx.x;
    const int w = tid >> 6, lane = tid & 63, quad = lane >> 4, ln = lane & 15;
    const int m0 = blockIdx.y * 128, n0 = blockIdx.x * 128;
    const unsigned short* BT = BTall + (size_t)blockIdx.z * (1024 * 1024);
    const float scl = (mode == 0 && blockIdx.z == 0) ? 0.180336878f : 1.0f;

    const int lr = lane >> 2;        // row within 16-row chunk
    const int lc = (lane & 3) * 8;   // elem offset within 32-elem row

    const f32x4 z4 = {0.f, 0.f, 0.f, 0.f};
    f32x4 acc[4][4];
#pragma unroll
    for (int i = 0; i < 4; i++)
#pragma unroll
        for (int j = 0; j < 4; j++) acc[i][j] = z4;

    const int wm = (w & 1) * 64, wn = (w >> 1) * 64;
    const int R0 = w * 32, R1 = w * 32 + 16;

    for (int k0 = 0; k0 < 1024; k0 += 32) {
        __syncthreads();
        gld16(As + R0 * 32, A  + (size_t)(m0 + R0 + lr) * 1024 + k0 + lc);
        gld16(As + R1 * 32, A  + (size_t)(m0 + R1 + lr) * 1024 + k0 + lc);
        gld16(Bs + R0 * 32, BT + (size_t)(n0 + R0 + lr) * 1024 + k0 + lc);
        gld16(Bs + R1 * 32, BT + (size_t)(n0 + R1 + lr) * 1024 + k0 + lc);
        __syncthreads();
        bf16x8 af[4], bfr[4];
#pragma unroll
        for (int t = 0; t < 4; t++)
            af[t] = *(const bf16x8*)&As[(wm + t * 16 + ln) * 32 + quad * 8];
#pragma unroll
        for (int t = 0; t < 4; t++)
            bfr[t] = *(const bf16x8*)&Bs[(wn + t * 16 + ln) * 32 + quad * 8];
#pragma unroll
        for (int tm = 0; tm < 4; tm++)
#pragma unroll
            for (int tn = 0; tn < 4; tn++)
                acc[tm][tn] = __builtin_amdgcn_mfma_f32_16x16x32_bf16(
                    af[tm], bfr[tn], acc[tm][tn], 0, 0, 0);
    }

#pragma unroll
    for (int tm = 0; tm < 4; tm++)
#pragma unroll
        for (int tn = 0; tn < 4; tn++) {
            int mg = m0 + wm + tm * 16 + quad * 4;
            int ng = n0 + wn + tn * 16 + ln;
#pragma unroll
            for (int r = 0; r < 4; r++) {
                float v = acc[tm][tn][r] * scl;
                int m = mg + r;
                if (mode == 0) {
                    int b = m >> 11, s = m & 2047, h = ng >> 6, d = ng & 63;
                    size_t zoff = (size_t)blockIdx.z * (4096 * 1024);
                    outq[zoff + (((size_t)(b * 16 + h) * 2048 + s) << 6) + d] = f2bf(v);
                } else {
                    outf[(size_t)m * 1024 + ng] = v;
                }
            }
        }
}

// ---------------- flash attention (causal, online softmax, exp2 domain) ----------------
// 64 q-rows/block (16/wave), 64-col k-tiles; Q frags register-resident.
// Balanced causal pairing over a flat 1024-block grid.
#define FD  72   // K/V LDS row stride (elems)
#define FDP 76   // P  LDS row stride (elems) — conflict-free b16 write groups
__global__ __launch_bounds__(256, 4) void flash(const unsigned short* __restrict__ Qb,
                                                const unsigned short* __restrict__ Kb,
                                                const unsigned short* __restrict__ Vtb,
                                                unsigned short* __restrict__ AO) {
    __shared__ unsigned short Ks[64 * FD];
    __shared__ unsigned short Vs[64 * FD];     // V^T tile: row=d, col=k-local
    __shared__ unsigned short Ps[4 * 16 * FDP];
    const int tid = threadIdx.x, w = tid >> 6, lane = tid & 63;
    const int quad = lane >> 4, ln = lane & 15;

    const int blk = blockIdx.x;
    const int bh  = blk & 31;
    const int jj  = (blk >> 5) & 15;
    const int qi  = (blk < 512) ? (16 + jj) : (15 - jj);   // heavy/light pairing
    const int qt0 = qi * 64;

    const unsigned short* Kg = Kb  + (size_t)bh * 2048 * 64;
    const unsigned short* Vg = Vtb + (size_t)bh * 64 * 2048;

    // Q fragments: loop-invariant, straight from global (A-frag: m=ln, k=ks*32+quad*8)
    bf16x8 aq[2];
    {
        const unsigned short* Qrow = Qb + ((size_t)bh * 2048 + qt0 + w * 16 + ln) * 64 + quad * 8;
        aq[0] = *(const bf16x8*)(Qrow);
        aq[1] = *(const bf16x8*)(Qrow + 32);
    }

    const f32x4 z4 = {0.f, 0.f, 0.f, 0.f};
    float mrow[4], lrow[4];
    f32x4 Oc[4];
#pragma unroll
    for (int r = 0; r < 4; r++) { mrow[r] = -INFINITY; lrow[r] = 0.f; }
#pragma unroll
    for (int tn = 0; tn < 4; tn++) Oc[tn] = z4;

    unsigned short* Pw = Ps + w * 16 * FDP;
    const int kend = qt0 + 64;

    for (int k0 = 0; k0 < kend; k0 += 64) {
        __syncthreads();
        {
            int c = tid, r = c >> 3, kc = (c & 7) * 8;
            *(uint4*)&Ks[r * FD + kc] = *(const uint4*)(Kg + (size_t)(k0 + r) * 64 + kc);
            *(uint4*)&Vs[r * FD + kc] = *(const uint4*)(Vg + (size_t)r * 2048 + k0 + kc);
            c = tid + 256; r = c >> 3; kc = (c & 7) * 8;
            *(uint4*)&Ks[r * FD + kc] = *(const uint4*)(Kg + (size_t)(k0 + r) * 64 + kc);
            *(uint4*)&Vs[r * FD + kc] = *(const uint4*)(Vg + (size_t)r * 2048 + k0 + kc);
        }
        __syncthreads();

        // S = Q K^T (scores already in exp2 domain via Q pre-scale)
        bf16x8 bk[4][2];
#pragma unroll
        for (int tn = 0; tn < 4; tn++)
#pragma unroll
            for (int ks = 0; ks < 2; ks++)
                bk[tn][ks] = *(const bf16x8*)&Ks[(tn * 16 + ln) * FD + ks * 32 + quad * 8];
        f32x4 sc[4];
#pragma unroll
        for (int tn = 0; tn < 4; tn++) sc[tn] = z4;
#pragma unroll
        for (int tn = 0; tn < 4; tn++) {
            sc[tn] = __builtin_amdgcn_mfma_f32_16x16x32_bf16(aq[0], bk[tn][0], sc[tn], 0, 0, 0);
            sc[tn] = __builtin_amdgcn_mfma_f32_16x16x32_bf16(aq[1], bk[tn][1], sc[tn], 0, 0, 0);
        }

        const bool edge = (k0 == qt0);   // only the diagonal tile needs masking
#pragma unroll
        for (int r = 0; r < 4; r++) {
            const int rowg = qt0 + w * 16 + quad * 4 + r;
            float sv[4];
            float mx = -INFINITY;
#pragma unroll
            for (int tn = 0; tn < 4; tn++) {
                float v = sc[tn][r];
                if (edge && (k0 + tn * 16 + ln) > rowg) v = -INFINITY;
                sv[tn] = v;
                mx = fmaxf(mx, v);
            }
#pragma unroll
            for (int off = 1; off < 16; off <<= 1) mx = fmaxf(mx, __shfl_xor(mx, off));
            float mold = mrow[r];
            float mnew = fmaxf(mold, mx);
            float alpha = exp2f(mold - mnew);
            mrow[r] = mnew;
            float rs = 0.f;
#pragma unroll
            for (int tn = 0; tn < 4; tn++) {
                float p = exp2f(sv[tn] - mnew);
                rs += p;
                Pw[(quad * 4 + r) * FDP + tn * 16 + ln] = f2bf(p);
            }
#pragma unroll
            for (int off = 1; off < 16; off <<= 1) rs += __shfl_xor(rs, off);
            lrow[r] = lrow[r] * alpha + rs;
#pragma unroll
            for (int tn = 0; tn < 4; tn++) Oc[tn][r] *= alpha;
        }

        // O += P V   (P from per-wave LDS scratch; no barrier needed — wave-private)
        bf16x8 ap[2], bv[4][2];
#pragma unroll
        for (int ks = 0; ks < 2; ks++)
            ap[ks] = *(const bf16x8*)&Pw[ln * FDP + ks * 32 + quad * 8];
#pragma unroll
        for (int tn = 0; tn < 4; tn++)
#pragma unroll
            for (int ks = 0; ks < 2; ks++)
                bv[tn][ks] = *(const bf16x8*)&Vs[(tn * 16 + ln) * FD + ks * 32 + quad * 8];
#pragma unroll
        for (int tn = 0; tn < 4; tn++) {
            Oc[tn] = __builtin_amdgcn_mfma_f32_16x16x32_bf16(ap[0], bv[tn][0], Oc[tn], 0, 0, 0);
            Oc[tn] = __builtin_amdgcn_mfma_f32_16x16x32_bf16(ap[1], bv[tn][1], Oc[tn], 0, 0, 0);
        }
    }

    const int bz = bh >> 4, h = bh & 15;
#pragma unroll
    for (int r = 0; r < 4; r++) {
        float inv = 1.0f / lrow[r];
        int rowg = qt0 + w * 16 + quad * 4 + r;
#pragma unroll
        for (int tn = 0; tn < 4; tn++) {
            float v = Oc[tn][r] * inv;
            AO[((size_t)(bz * 2048 + rowg) << 10) + h * 64 + tn * 16 + ln] = f2bf(v);
        }
    }
}

extern "C" void kernel_launch(void* const* d_in, const int* in_sizes, int n_in,
                              void* d_out, int out_size, void* d_ws, size_t ws_size,
                              hipStream_t stream) {
    const float* x  = (const float*)d_in[0];
    const float* Wq = (const float*)d_in[1];
    const float* Wk = (const float*)d_in[2];
    const float* Wv = (const float*)d_in[3];
    const float* Wo = (const float*)d_in[4];
    float* out = (float*)d_out;

    unsigned short* xb  = (unsigned short*)d_ws;           // 4096*1024
    unsigned short* WT  = xb  + (size_t)4096 * 1024;       // 4*1024*1024
    unsigned short* Qb  = WT  + (size_t)4 * 1024 * 1024;   // Q,K,V contiguous
    unsigned short* Kb  = Qb  + (size_t)4096 * 1024;
    unsigned short* Vb  = Kb  + (size_t)4096 * 1024;
    unsigned short* Vtb = Vb  + (size_t)4096 * 1024;
    unsigned short* AO  = Vtb + (size_t)4096 * 1024;

    castx<<<4096, 256, 0, stream>>>(x, xb);
    wtrans<<<dim3(16, 16, 4), 256, 0, stream>>>(Wq, Wk, Wv, Wo, WT);
    gemm_bt<<<dim3(8, 32, 3), 256, 0, stream>>>(xb, WT, Qb, nullptr, 0);
    vtrans<<<dim3(32, 32), 256, 0, stream>>>(Vb, Vtb);
    flash<<<dim3(1024), 256, 0, stream>>>(Qb, Kb, Vtb, AO);
    gemm_bt<<<dim3(8, 32, 1), 256, 0, stream>>>(AO, WT + (size_t)3 * 1024 * 1024,
                                                nullptr, out, 1);
}